// Round 11
// baseline (294.988 us; speedup 1.0000x reference)
//
#include <hip/hip_runtime.h>
#include <hip/hip_bf16.h>
#include <math.h>

#define N_TOKENS 32768
#define HIDDEN   2048
#define NEXP     8
#define H4       (HIDDEN / 4)            // 512 float4 per row
#define BLOCK    512                     // 8 waves: the regime where the
                                         // compiler allocates ~128 VGPR (r9)
#define WPB      (BLOCK / 64)
#define TOK_PER_WAVE 8                   // 4 passes x 2 tokens
#define GRID     (N_TOKENS / (WPB * TOK_PER_WAVE))   // 512 blocks

#define SCORES_OFF 0
#define IDX_OFF    (N_TOKENS * 2)        // 65536
#define HIST_OFF   (N_TOKENS * 4)        // 131072

__global__ void zero_hist_kernel(float* out) {
    if (threadIdx.x < NEXP) out[HIST_OFF + threadIdx.x] = 0.0f;
}

// top-2 with lowest-index tie-break (strict >), matching jax.lax.top_k.
// cnt: packed 8-bit per-expert counters (8 tokens/wave -> max 16, fits).
__device__ __forceinline__ void emit_token(const double* acc, int t,
                                           float* __restrict__ out,
                                           unsigned long long* cnt) {
    double b1 = acc[0]; int i1 = 0;
    double b2 = -1.0e300; int i2 = 0;
#pragma unroll
    for (int e = 1; e < NEXP; ++e) {
        double v = acc[e];
        if (v > b1)      { b2 = b1; i2 = i1; b1 = v; i1 = e; }
        else if (v > b2) { b2 = v;  i2 = e; }
    }
    float d  = (float)(b2 - b1);
    float e1 = expf(d);
    float s0 = 1.0f / (1.0f + e1);

    float2 sc; sc.x = s0; sc.y = e1 * s0;
    float2 ix; ix.x = (float)i1; ix.y = (float)i2;
    *reinterpret_cast<float2*>(out + SCORES_OFF + 2 * t) = sc;
    *reinterpret_cast<float2*>(out + IDX_OFF    + 2 * t) = ix;

    *cnt += (1ull << (8 * i1)) + (1ull << (8 * i2));
}

// r7 numerics (bit-identical sums) in the 512-thread register regime,
// + depth-1 k-pair prefetch and cross-pass prefetch: next pair's 4 x-loads
// are in flight while the current pair (and, at pass end, the reduction/
// emit) execute. Live set ~90 VGPR < the 128 cap of (512,4) -- r9 proved
// this regime doesn't spill at ~115 live.
__global__ __launch_bounds__(BLOCK, 4) void router_kernel(
        const float* __restrict__ x, const float* __restrict__ W,
        float* __restrict__ out) {
    __shared__ float4 wlds[NEXP * H4];   // 64 KiB

    const int tid = threadIdx.x;
    const float4* Wv = reinterpret_cast<const float4*>(W);
#pragma unroll
    for (int i = 0; i < (NEXP * H4) / BLOCK; ++i)
        wlds[tid + i * BLOCK] = Wv[tid + i * BLOCK];
    __syncthreads();

    const int wave  = tid >> 6;
    const int lane  = tid & 63;
    const int tbase = (blockIdx.x * WPB + wave) * TOK_PER_WAVE;
    const float4* X = reinterpret_cast<const float4*>(x);

    unsigned long long cnt = 0;

    // pre-issue pass 0's first k-pair (tokens tbase, tbase+1; k=0,1)
    const float4* xa_p = X + (size_t)tbase * H4;
    const float4* xb_p = xa_p + H4;
    float4 a0n = xa_p[lane], a1n = xa_p[lane + 64];
    float4 b0n = xb_p[lane], b1n = xb_p[lane + 64];

#pragma unroll 1
    for (int p = 0; p < TOK_PER_WAVE / 2; ++p) {
        const int t0 = tbase + 2 * p;
        const float4* xa = X + (size_t)t0 * H4;
        const float4* xb = xa + H4;

        // acc[0..7] = token a, acc[8..15] = token b
        double acc[16];
#pragma unroll
        for (int e = 0; e < 16; ++e) acc[e] = 0.0;

        float4 a0c = a0n, a1c = a1n, b0c = b0n, b1c = b1n;

#pragma unroll
        for (int kk = 0; kk < 8; kk += 2) {   // 4 static iterations
            // prefetch: next k-pair, or next pass's first pair (in flight
            // across the reduction/emit below)
            if (kk < 6) {
                a0n = xa[lane + (kk + 2) * 64]; a1n = xa[lane + (kk + 3) * 64];
                b0n = xb[lane + (kk + 2) * 64]; b1n = xb[lane + (kk + 3) * 64];
            } else if (p < TOK_PER_WAVE / 2 - 1) {
                a0n = xa[lane + 2 * H4]; a1n = xa[lane + 64 + 2 * H4];
                b0n = xb[lane + 2 * H4]; b1n = xb[lane + 64 + 2 * H4];
            }
#pragma unroll
            for (int e = 0; e < NEXP; ++e) {
                const float4 w0 = wlds[e * H4 + lane + kk * 64];
                float s0 = w0.x * a0c.x;
                s0 = fmaf(w0.y, a0c.y, s0); s0 = fmaf(w0.z, a0c.z, s0); s0 = fmaf(w0.w, a0c.w, s0);
                float s1 = w0.x * b0c.x;
                s1 = fmaf(w0.y, b0c.y, s1); s1 = fmaf(w0.z, b0c.z, s1); s1 = fmaf(w0.w, b0c.w, s1);
                const float4 w1 = wlds[e * H4 + lane + (kk + 1) * 64];
                s0 = fmaf(w1.x, a1c.x, s0); s0 = fmaf(w1.y, a1c.y, s0);
                s0 = fmaf(w1.z, a1c.z, s0); s0 = fmaf(w1.w, a1c.w, s0);
                s1 = fmaf(w1.x, b1c.x, s1); s1 = fmaf(w1.y, b1c.y, s1);
                s1 = fmaf(w1.z, b1c.z, s1); s1 = fmaf(w1.w, b1c.w, s1);
                // one f64 accumulate per 8 elements (identical to r7)
                acc[e]     += (double)s0;
                acc[8 + e] += (double)s1;
            }
            a0c = a0n; a1c = a1n; b0c = b0n; b1c = b1n;
        }

        // reduce-scatter butterfly (verified r6/r7/r9): masks 1,2,4,8 halve
        // 16 values/lane -> 1, then 16,32 finish. Bit-identical totals to
        // the full butterfly (same pairing, commutative adds).
        {
            const bool u1 = lane & 1;
#pragma unroll
            for (int i = 0; i < 8; ++i) {
                double send = u1 ? acc[i] : acc[8 + i];
                double got  = __shfl_xor(send, 1, 64);
                acc[i] = (u1 ? acc[8 + i] : acc[i]) + got;
            }
            const bool u2 = lane & 2;
#pragma unroll
            for (int i = 0; i < 4; ++i) {
                double send = u2 ? acc[i] : acc[4 + i];
                double got  = __shfl_xor(send, 2, 64);
                acc[i] = (u2 ? acc[4 + i] : acc[i]) + got;
            }
            const bool u4 = lane & 4;
#pragma unroll
            for (int i = 0; i < 2; ++i) {
                double send = u4 ? acc[i] : acc[2 + i];
                double got  = __shfl_xor(send, 4, 64);
                acc[i] = (u4 ? acc[2 + i] : acc[i]) + got;
            }
            const bool u8 = lane & 8;
            {
                double send = u8 ? acc[0] : acc[1];
                double got  = __shfl_xor(send, 8, 64);
                acc[0] = (u8 ? acc[1] : acc[0]) + got;
            }
            acc[0] += __shfl_xor(acc[0], 16, 64);
            acc[0] += __shfl_xor(acc[0], 32, 64);
        }
        // value j sits at lane bitrev4(j): token a (j=e) at r, token b at r+1
        double v0[NEXP], v1[NEXP];
#pragma unroll
        for (int e = 0; e < NEXP; ++e) {
            const int r = ((e & 1) << 3) | ((e & 2) << 1) | ((e & 4) >> 1);
            v0[e] = __shfl(acc[0], r,     64);
            v1[e] = __shfl(acc[0], r + 1, 64);
        }
        if (lane == 0) {
            emit_token(v0, t0,     out, &cnt);
            emit_token(v1, t0 + 1, out, &cnt);
        }
    }

    // block histogram: reuse wlds as scratch after all waves done with W
    __syncthreads();
    float* h = reinterpret_cast<float*>(wlds);
    if (tid < NEXP) h[tid] = 0.0f;
    __syncthreads();
    if (lane == 0) {
#pragma unroll
        for (int e = 0; e < NEXP; ++e) {
            const unsigned c = (unsigned)((cnt >> (8 * e)) & 0xFFull);
            if (c) atomicAdd(&h[e], (float)c);
        }
    }
    __syncthreads();
    if (tid < NEXP) atomicAdd(&out[HIST_OFF + tid], h[tid]);
}

extern "C" void kernel_launch(void* const* d_in, const int* in_sizes, int n_in,
                              void* d_out, int out_size, void* d_ws, size_t ws_size,
                              hipStream_t stream) {
    const float* x = (const float*)d_in[0];
    const float* W = (const float*)d_in[1];
    float* out = (float*)d_out;

    zero_hist_kernel<<<1, 64, 0, stream>>>(out);
    router_kernel<<<GRID, BLOCK, 0, stream>>>(x, W, out);
}

// Round 12
// 121.199 us; speedup vs baseline: 2.4339x; 2.4339x over previous
//
#include <hip/hip_runtime.h>
#include <hip/hip_bf16.h>
#include <math.h>

#define N_TOKENS 32768
#define HIDDEN   2048
#define NEXP     8
#define H4       (HIDDEN / 4)            // 512 float4 per row
#define BLOCK    256                     // 4 waves, no big LDS -> 8 blocks/CU
#define WPB      (BLOCK / 64)
#define TOK_PER_WAVE 4
#define GRID     (N_TOKENS / (WPB * TOK_PER_WAVE))   // 2048 blocks

#define SCORES_OFF 0
#define IDX_OFF    (N_TOKENS * 2)        // 65536
#define HIST_OFF   (N_TOKENS * 4)        // 131072

__global__ void zero_hist_kernel(float* out) {
    if (threadIdx.x < NEXP) out[HIST_OFF + threadIdx.x] = 0.0f;
}

// top-2 with lowest-index tie-break (strict >), matching jax.lax.top_k.
// cnt: packed 4-bit per-expert counters (max 4 tokens/wave -> fits).
__device__ __forceinline__ void emit_token(const double* acc, int t,
                                           float* __restrict__ out, unsigned* cnt) {
    double b1 = acc[0]; int i1 = 0;
    double b2 = -1.0e300; int i2 = 0;
#pragma unroll
    for (int e = 1; e < NEXP; ++e) {
        double v = acc[e];
        if (v > b1)      { b2 = b1; i2 = i1; b1 = v; i1 = e; }
        else if (v > b2) { b2 = v;  i2 = e; }
    }
    float d  = (float)(b2 - b1);
    float e1 = expf(d);
    float s0 = 1.0f / (1.0f + e1);

    float2 sc; sc.x = s0; sc.y = e1 * s0;
    float2 ix; ix.x = (float)i1; ix.y = (float)i2;
    *reinterpret_cast<float2*>(out + SCORES_OFF + 2 * t) = sc;
    *reinterpret_cast<float2*>(out + IDX_OFF    + 2 * t) = ix;

    *cnt += (1u << (4 * i1)) + (1u << (4 * i2));
}

// r7 numerics with W read DIRECTLY from global (L2-resident 64 KB):
//  - no 64 KB LDS -> 8 blocks/CU (32 waves/CU, 2x r7's occupancy for
//    hiding the x-stream latency), no staging barrier
//  - W HBM re-fetch drops from 512x64KB (~35 MB) to ~8x64KB (first touch
//    per XCD L2)
//  - unlike round 8: e-loop FULLY unrolled so every acc[] index is a
//    compile-time constant (r8's unroll-1 e-loop put acc in scratch ->
//    670 MB spill; rule #20). Live set ~62 <= the 64-VGPR cap of (256,8).
// Per-token sums bit-identical to r7: same 8-elem f32 dot groups, same
// f64 butterfly tree (masks 1,2,4,8,16,32 in order).
__global__ __launch_bounds__(BLOCK, 8) void router_kernel(
        const float* __restrict__ x, const float* __restrict__ W,
        float* __restrict__ out) {
    __shared__ float h[NEXP];            // 32 B only

    const int tid  = threadIdx.x;
    const int wave = tid >> 6;
    const int lane = tid & 63;
    const int gw   = blockIdx.x * WPB + wave;

    if (tid < NEXP) h[tid] = 0.0f;
    __syncthreads();

    const float4* Wv = reinterpret_cast<const float4*>(W);
    unsigned cnt = 0;

#pragma unroll 1
    for (int p = 0; p < TOK_PER_WAVE / 2; ++p) {
        const int t0 = gw * TOK_PER_WAVE + 2 * p;
        const float4* xa = reinterpret_cast<const float4*>(x) + (size_t)t0 * H4;
        const float4* xb = xa + H4;

        // acc[0..7] = token a, acc[8..15] = token b
        double acc[16];
#pragma unroll
        for (int e = 0; e < 16; ++e) acc[e] = 0.0;

#pragma unroll 1
        for (int k = 0; k < 8; k += 2) {     // 4 iterations, 8-elem dot groups
            const float4 a0 = xa[lane + k * 64];
            const float4 a1 = xa[lane + (k + 1) * 64];
            const float4 b0 = xb[lane + k * 64];
            const float4 b1 = xb[lane + (k + 1) * 64];
#pragma unroll
            for (int e = 0; e < NEXP; ++e) {     // FULL unroll: static acc idx
                const float4 w0 = Wv[e * H4 + lane + k * 64];        // L2 hit
                const float4 w1 = Wv[e * H4 + lane + (k + 1) * 64];
                float s0 = w0.x * a0.x;
                s0 = fmaf(w0.y, a0.y, s0); s0 = fmaf(w0.z, a0.z, s0); s0 = fmaf(w0.w, a0.w, s0);
                float s1 = w0.x * b0.x;
                s1 = fmaf(w0.y, b0.y, s1); s1 = fmaf(w0.z, b0.z, s1); s1 = fmaf(w0.w, b0.w, s1);
                s0 = fmaf(w1.x, a1.x, s0); s0 = fmaf(w1.y, a1.y, s0);
                s0 = fmaf(w1.z, a1.z, s0); s0 = fmaf(w1.w, a1.w, s0);
                s1 = fmaf(w1.x, b1.x, s1); s1 = fmaf(w1.y, b1.y, s1);
                s1 = fmaf(w1.z, b1.z, s1); s1 = fmaf(w1.w, b1.w, s1);
                acc[e]     += (double)s0;    // one f64 accumulate per 8 elems
                acc[8 + e] += (double)s1;
            }
        }

        // reduce-scatter butterfly (verified r6/r7): masks 1,2,4,8 halve
        // 16 values/lane -> 1, then 16,32 finish. Bit-identical totals to
        // the full butterfly (same pairing, commutative adds).
        {
            const bool u1 = lane & 1;
#pragma unroll
            for (int i = 0; i < 8; ++i) {
                double send = u1 ? acc[i] : acc[8 + i];
                double got  = __shfl_xor(send, 1, 64);
                acc[i] = (u1 ? acc[8 + i] : acc[i]) + got;
            }
            const bool u2 = lane & 2;
#pragma unroll
            for (int i = 0; i < 4; ++i) {
                double send = u2 ? acc[i] : acc[4 + i];
                double got  = __shfl_xor(send, 2, 64);
                acc[i] = (u2 ? acc[4 + i] : acc[i]) + got;
            }
            const bool u4 = lane & 4;
#pragma unroll
            for (int i = 0; i < 2; ++i) {
                double send = u4 ? acc[i] : acc[2 + i];
                double got  = __shfl_xor(send, 4, 64);
                acc[i] = (u4 ? acc[2 + i] : acc[i]) + got;
            }
            const bool u8 = lane & 8;
            {
                double send = u8 ? acc[0] : acc[1];
                double got  = __shfl_xor(send, 8, 64);
                acc[0] = (u8 ? acc[1] : acc[0]) + got;
            }
            acc[0] += __shfl_xor(acc[0], 16, 64);
            acc[0] += __shfl_xor(acc[0], 32, 64);
        }
        // value j sits at lane bitrev4(j): token a (j=e) at r, token b at r+1
        double v0[NEXP], v1[NEXP];
#pragma unroll
        for (int e = 0; e < NEXP; ++e) {
            const int r = ((e & 1) << 3) | ((e & 2) << 1) | ((e & 4) >> 1);
            v0[e] = __shfl(acc[0], r,     64);
            v1[e] = __shfl(acc[0], r + 1, 64);
        }
        if (lane == 0) {
            emit_token(v0, t0,     out, &cnt);
            emit_token(v1, t0 + 1, out, &cnt);
        }
    }

    // block histogram: tiny LDS reduce, then one atomic per expert per block
    if (lane == 0) {
#pragma unroll
        for (int e = 0; e < NEXP; ++e) {
            const unsigned c = (cnt >> (4 * e)) & 0xFu;
            if (c) atomicAdd(&h[e], (float)c);
        }
    }
    __syncthreads();
    if (tid < NEXP) atomicAdd(&out[HIST_OFF + tid], h[tid]);
}

extern "C" void kernel_launch(void* const* d_in, const int* in_sizes, int n_in,
                              void* d_out, int out_size, void* d_ws, size_t ws_size,
                              hipStream_t stream) {
    const float* x = (const float*)d_in[0];
    const float* W = (const float*)d_in[1];
    float* out = (float*)d_out;

    zero_hist_kernel<<<1, 64, 0, stream>>>(out);
    router_kernel<<<GRID, BLOCK, 0, stream>>>(x, W, out);
}

// Round 13
// 91.933 us; speedup vs baseline: 3.2087x; 1.3183x over previous
//
#include <hip/hip_runtime.h>
#include <hip/hip_bf16.h>
#include <math.h>

#define N_TOKENS 32768
#define HIDDEN   2048
#define NEXP     8
#define H4       (HIDDEN / 4)            // 512 float4 per row
#define HHALF    256                     // float4 per row-half
#define BLOCK    1024                    // 16 waves
#define WPB      (BLOCK / 64)
#define TOK_PER_WAVE 2                   // acc must persist across W halves
#define GRID     (N_TOKENS / (WPB * TOK_PER_WAVE))   // 1024 blocks

#define SCORES_OFF 0
#define IDX_OFF    (N_TOKENS * 2)        // 65536
#define HIST_OFF   (N_TOKENS * 4)        // 131072

__global__ void zero_hist_kernel(float* out) {
    if (threadIdx.x < NEXP) out[HIST_OFF + threadIdx.x] = 0.0f;
}

// top-2 with lowest-index tie-break (strict >), matching jax.lax.top_k.
// cnt: packed 4-bit per-expert counters (max 2 tokens/wave -> fits).
__device__ __forceinline__ void emit_token(const double* acc, int t,
                                           float* __restrict__ out, unsigned* cnt) {
    double b1 = acc[0]; int i1 = 0;
    double b2 = -1.0e300; int i2 = 0;
#pragma unroll
    for (int e = 1; e < NEXP; ++e) {
        double v = acc[e];
        if (v > b1)      { b2 = b1; i2 = i1; b1 = v; i1 = e; }
        else if (v > b2) { b2 = v;  i2 = e; }
    }
    float d  = (float)(b2 - b1);
    float e1 = expf(d);
    float s0 = 1.0f / (1.0f + e1);

    float2 sc; sc.x = s0; sc.y = e1 * s0;
    float2 ix; ix.x = (float)i1; ix.y = (float)i2;
    *reinterpret_cast<float2*>(out + SCORES_OFF + 2 * t) = sc;
    *reinterpret_cast<float2*>(out + IDX_OFF    + 2 * t) = ix;

    *cnt += (1u << (4 * i1)) + (1u << (4 * i2));
}

// r7 numerics with W staged in TWO 32 KB K-halves instead of one 64 KB
// buffer. Occupancy hypothesis: 64 KB-LDS blocks only reach 1 block/CU
// (16 waves, r1/r2/r6 counters all ~48%); 32 KB -> 2 blocks = 32 waves/CU.
// Same 8-elem f32 dot groups added to acc in the SAME ascending order
// (half0 = k-pairs {0,1}{2,3}, half1 = {4,5}{6,7}) -> per-token sums
// bit-identical to r7; butterfly/emit unchanged.
__global__ __launch_bounds__(BLOCK, 8) void router_kernel(
        const float* __restrict__ x, const float* __restrict__ W,
        float* __restrict__ out) {
    __shared__ float4 wlds[NEXP * HHALF];   // 32 KiB: [e][256] for current half

    const int tid  = threadIdx.x;
    const int wave = tid >> 6;
    const int lane = tid & 63;
    const int t0   = (blockIdx.x * WPB + wave) * TOK_PER_WAVE;

    const float4* Wv = reinterpret_cast<const float4*>(W);
    const float4* xa = reinterpret_cast<const float4*>(x) + (size_t)t0 * H4;
    const float4* xb = xa + H4;

    unsigned cnt = 0;

    // acc[0..7] = token a, acc[8..15] = token b; persists across halves
    double acc[16];
#pragma unroll
    for (int e = 0; e < 16; ++e) acc[e] = 0.0;

#pragma unroll 1
    for (int hh = 0; hh < 2; ++hh) {
        if (hh) __syncthreads();         // all waves done reading prev half
        // stage this 32 KB half: 2 float4 per thread
#pragma unroll
        for (int i = 0; i < 2; ++i) {
            const int f = tid + i * BLOCK;          // 0..2047
            const int e = f >> 8, c = f & (HHALF - 1);
            wlds[f] = Wv[e * H4 + hh * HHALF + c];
        }
        __syncthreads();

        const int hb = hh * HHALF;
#pragma unroll 1
        for (int k = 0; k < 4; k += 2) {     // 2 iterations, 8-elem dot groups
            const float4 a0 = xa[hb + lane + k * 64];
            const float4 a1 = xa[hb + lane + (k + 1) * 64];
            const float4 b0 = xb[hb + lane + k * 64];
            const float4 b1 = xb[hb + lane + (k + 1) * 64];
#pragma unroll
            for (int e = 0; e < NEXP; ++e) {
                const float4 w0 = wlds[e * HHALF + lane + k * 64];
                float s0 = w0.x * a0.x;
                s0 = fmaf(w0.y, a0.y, s0); s0 = fmaf(w0.z, a0.z, s0); s0 = fmaf(w0.w, a0.w, s0);
                float s1 = w0.x * b0.x;
                s1 = fmaf(w0.y, b0.y, s1); s1 = fmaf(w0.z, b0.z, s1); s1 = fmaf(w0.w, b0.w, s1);
                const float4 w1 = wlds[e * HHALF + lane + (k + 1) * 64];
                s0 = fmaf(w1.x, a1.x, s0); s0 = fmaf(w1.y, a1.y, s0);
                s0 = fmaf(w1.z, a1.z, s0); s0 = fmaf(w1.w, a1.w, s0);
                s1 = fmaf(w1.x, b1.x, s1); s1 = fmaf(w1.y, b1.y, s1);
                s1 = fmaf(w1.z, b1.z, s1); s1 = fmaf(w1.w, b1.w, s1);
                // one f64 accumulate per 8 elements (identical to r7)
                acc[e]     += (double)s0;
                acc[8 + e] += (double)s1;
            }
        }
    }

    // reduce-scatter butterfly (verified r6/r7): masks 1,2,4,8 halve
    // 16 values/lane -> 1, then 16,32 finish. Bit-identical totals to
    // the full butterfly (same pairing, commutative adds).
    {
        const bool u1 = lane & 1;
#pragma unroll
        for (int i = 0; i < 8; ++i) {
            double send = u1 ? acc[i] : acc[8 + i];
            double got  = __shfl_xor(send, 1, 64);
            acc[i] = (u1 ? acc[8 + i] : acc[i]) + got;
        }
        const bool u2 = lane & 2;
#pragma unroll
        for (int i = 0; i < 4; ++i) {
            double send = u2 ? acc[i] : acc[4 + i];
            double got  = __shfl_xor(send, 2, 64);
            acc[i] = (u2 ? acc[4 + i] : acc[i]) + got;
        }
        const bool u4 = lane & 4;
#pragma unroll
        for (int i = 0; i < 2; ++i) {
            double send = u4 ? acc[i] : acc[2 + i];
            double got  = __shfl_xor(send, 4, 64);
            acc[i] = (u4 ? acc[2 + i] : acc[i]) + got;
        }
        const bool u8 = lane & 8;
        {
            double send = u8 ? acc[0] : acc[1];
            double got  = __shfl_xor(send, 8, 64);
            acc[0] = (u8 ? acc[1] : acc[0]) + got;
        }
        acc[0] += __shfl_xor(acc[0], 16, 64);
        acc[0] += __shfl_xor(acc[0], 32, 64);
    }
    // value j sits at lane bitrev4(j): token a (j=e) at r, token b at r+1
    double v0[NEXP], v1[NEXP];
#pragma unroll
    for (int e = 0; e < NEXP; ++e) {
        const int r = ((e & 1) << 3) | ((e & 2) << 1) | ((e & 4) >> 1);
        v0[e] = __shfl(acc[0], r,     64);
        v1[e] = __shfl(acc[0], r + 1, 64);
    }
    if (lane == 0) {
        emit_token(v0, t0,     out, &cnt);
        emit_token(v1, t0 + 1, out, &cnt);
    }

    // block histogram: reuse wlds as scratch after all waves done with W
    __syncthreads();
    float* h = reinterpret_cast<float*>(wlds);
    if (tid < NEXP) h[tid] = 0.0f;
    __syncthreads();
    if (lane == 0) {
#pragma unroll
        for (int e = 0; e < NEXP; ++e) {
            const unsigned c = (cnt >> (4 * e)) & 0xFu;
            if (c) atomicAdd(&h[e], (float)c);
        }
    }
    __syncthreads();
    if (tid < NEXP) atomicAdd(&out[HIST_OFF + tid], h[tid]);
}

extern "C" void kernel_launch(void* const* d_in, const int* in_sizes, int n_in,
                              void* d_out, int out_size, void* d_ws, size_t ws_size,
                              hipStream_t stream) {
    const float* x = (const float*)d_in[0];
    const float* W = (const float*)d_in[1];
    float* out = (float*)d_out;

    zero_hist_kernel<<<1, 64, 0, stream>>>(out);
    router_kernel<<<GRID, BLOCK, 0, stream>>>(x, W, out);
}

// Round 14
// 62.462 us; speedup vs baseline: 4.7227x; 1.4718x over previous
//
#include <hip/hip_runtime.h>
#include <hip/hip_bf16.h>
#include <math.h>

#define N_TOKENS 32768
#define HIDDEN   2048
#define NEXP     8
#define H4       (HIDDEN / 4)            // 512 float4 per row
#define BLOCK    1024                    // 16 waves
#define WPB      (BLOCK / 64)
#define TOK_PER_WAVE 4
#define GRID     (N_TOKENS / (WPB * TOK_PER_WAVE))   // 512 blocks = 2/CU

#define SCORES_OFF 0
#define IDX_OFF    (N_TOKENS * 2)        // 65536
#define HIST_OFF   (N_TOKENS * 4)        // 131072

__global__ void zero_hist_kernel(float* out) {
    if (threadIdx.x < NEXP) out[HIST_OFF + threadIdx.x] = 0.0f;
}

// top-2 with lowest-index tie-break (strict >), matching jax.lax.top_k.
// cnt: packed 4-bit per-expert counters (max 4 tokens/wave -> fits).
__device__ __forceinline__ void emit_token(const double* acc, int t,
                                           float* __restrict__ out, unsigned* cnt) {
    double b1 = acc[0]; int i1 = 0;
    double b2 = -1.0e300; int i2 = 0;
#pragma unroll
    for (int e = 1; e < NEXP; ++e) {
        double v = acc[e];
        if (v > b1)      { b2 = b1; i2 = i1; b1 = v; i1 = e; }
        else if (v > b2) { b2 = v;  i2 = e; }
    }
    float d  = (float)(b2 - b1);
    float e1 = expf(d);
    float s0 = 1.0f / (1.0f + e1);

    float2 sc; sc.x = s0; sc.y = e1 * s0;
    float2 ix; ix.x = (float)i1; ix.y = (float)i2;
    *reinterpret_cast<float2*>(out + SCORES_OFF + 2 * t) = sc;
    *reinterpret_cast<float2*>(out + IDX_OFF    + 2 * t) = ix;

    *cnt += (1u << (4 * i1)) + (1u << (4 * i2));
}

// Round-7 champion, reverted verbatim (62.4 us; best of 13 rounds).
// Wave-owns-token-pair, W broadcast from 64 KB LDS, coalesced x->regs.
// Designed to the hard 64-VGPR budget the allocator pins at 64KB LDS:
//  - 8-elem f32 dot groups (halves f64 cvt/add; error class proven r4/r5)
//  - reduce-scatter butterfly (17 f64 shuffles vs 96; verified r6+)
//  - packed histogram counters (1 reg vs 8); no software prefetch (the
//    allocator wall: r6/r8/r11 all spilled to scratch attempting it)
__global__ __launch_bounds__(BLOCK, 4) void router_kernel(
        const float* __restrict__ x, const float* __restrict__ W,
        float* __restrict__ out) {
    __shared__ float4 wlds[NEXP * H4];   // 64 KiB

    const int tid = threadIdx.x;
    const float4* Wv = reinterpret_cast<const float4*>(W);
#pragma unroll
    for (int i = 0; i < (NEXP * H4) / BLOCK; ++i)
        wlds[tid + i * BLOCK] = Wv[tid + i * BLOCK];
    __syncthreads();

    const int wave = tid >> 6;
    const int lane = tid & 63;
    const int gw   = blockIdx.x * WPB + wave;

    unsigned cnt = 0;

#pragma unroll 1
    for (int p = 0; p < TOK_PER_WAVE / 2; ++p) {
        const int t0 = gw * TOK_PER_WAVE + 2 * p;
        const float4* xa = reinterpret_cast<const float4*>(x) + (size_t)t0 * H4;
        const float4* xb = xa + H4;

        // acc[0..7] = token a, acc[8..15] = token b
        double acc[16];
#pragma unroll
        for (int e = 0; e < 16; ++e) acc[e] = 0.0;

#pragma unroll 1
        for (int k = 0; k < 8; k += 2) {     // 4 iterations, 8-elem dot groups
            const float4 a0 = xa[lane + k * 64];
            const float4 a1 = xa[lane + (k + 1) * 64];
            const float4 b0 = xb[lane + k * 64];
            const float4 b1 = xb[lane + (k + 1) * 64];
#pragma unroll
            for (int e = 0; e < NEXP; ++e) {
                const float4 w0 = wlds[e * H4 + lane + k * 64];
                float s0 = w0.x * a0.x;
                s0 = fmaf(w0.y, a0.y, s0); s0 = fmaf(w0.z, a0.z, s0); s0 = fmaf(w0.w, a0.w, s0);
                float s1 = w0.x * b0.x;
                s1 = fmaf(w0.y, b0.y, s1); s1 = fmaf(w0.z, b0.z, s1); s1 = fmaf(w0.w, b0.w, s1);
                const float4 w1 = wlds[e * H4 + lane + (k + 1) * 64];
                s0 = fmaf(w1.x, a1.x, s0); s0 = fmaf(w1.y, a1.y, s0);
                s0 = fmaf(w1.z, a1.z, s0); s0 = fmaf(w1.w, a1.w, s0);
                s1 = fmaf(w1.x, b1.x, s1); s1 = fmaf(w1.y, b1.y, s1);
                s1 = fmaf(w1.z, b1.z, s1); s1 = fmaf(w1.w, b1.w, s1);
                // one f64 accumulate per 8 elements
                acc[e]     += (double)s0;
                acc[8 + e] += (double)s1;
            }
        }

        // reduce-scatter butterfly (verified r6/r7): masks 1,2,4,8 halve
        // 16 values/lane -> 1, then 16,32 finish. Bit-identical totals to
        // the full butterfly (same pairing, commutative adds).
        {
            const bool u1 = lane & 1;
#pragma unroll
            for (int i = 0; i < 8; ++i) {
                double send = u1 ? acc[i] : acc[8 + i];
                double got  = __shfl_xor(send, 1, 64);
                acc[i] = (u1 ? acc[8 + i] : acc[i]) + got;
            }
            const bool u2 = lane & 2;
#pragma unroll
            for (int i = 0; i < 4; ++i) {
                double send = u2 ? acc[i] : acc[4 + i];
                double got  = __shfl_xor(send, 2, 64);
                acc[i] = (u2 ? acc[4 + i] : acc[i]) + got;
            }
            const bool u4 = lane & 4;
#pragma unroll
            for (int i = 0; i < 2; ++i) {
                double send = u4 ? acc[i] : acc[2 + i];
                double got  = __shfl_xor(send, 4, 64);
                acc[i] = (u4 ? acc[2 + i] : acc[i]) + got;
            }
            const bool u8 = lane & 8;
            {
                double send = u8 ? acc[0] : acc[1];
                double got  = __shfl_xor(send, 8, 64);
                acc[0] = (u8 ? acc[1] : acc[0]) + got;
            }
            acc[0] += __shfl_xor(acc[0], 16, 64);
            acc[0] += __shfl_xor(acc[0], 32, 64);
        }
        // value j sits at lane bitrev4(j): token a (j=e) at r, token b at r+1
        double v0[NEXP], v1[NEXP];
#pragma unroll
        for (int e = 0; e < NEXP; ++e) {
            const int r = ((e & 1) << 3) | ((e & 2) << 1) | ((e & 4) >> 1);
            v0[e] = __shfl(acc[0], r,     64);
            v1[e] = __shfl(acc[0], r + 1, 64);
        }
        if (lane == 0) {
            emit_token(v0, t0,     out, &cnt);
            emit_token(v1, t0 + 1, out, &cnt);
        }
    }

    // block histogram: reuse wlds as scratch after all waves done with W
    __syncthreads();
    float* h = reinterpret_cast<float*>(wlds);
    if (tid < NEXP) h[tid] = 0.0f;
    __syncthreads();
    if (lane == 0) {
#pragma unroll
        for (int e = 0; e < NEXP; ++e) {
            const unsigned c = (cnt >> (4 * e)) & 0xFu;
            if (c) atomicAdd(&h[e], (float)c);
        }
    }
    __syncthreads();
    if (tid < NEXP) atomicAdd(&out[HIST_OFF + tid], h[tid]);
}

extern "C" void kernel_launch(void* const* d_in, const int* in_sizes, int n_in,
                              void* d_out, int out_size, void* d_ws, size_t ws_size,
                              hipStream_t stream) {
    const float* x = (const float*)d_in[0];
    const float* W = (const float*)d_in[1];
    float* out = (float*)d_out;

    zero_hist_kernel<<<1, 64, 0, stream>>>(out);
    router_kernel<<<GRID, BLOCK, 0, stream>>>(x, W, out);
}